// Round 4
// baseline (150.774 us; speedup 1.0000x reference)
//
#include <hip/hip_runtime.h>
#include <math.h>

#define D_MODEL 512
#define NHEADS  8
#define NSEQ    2048
#define NBLK    16
#define NCHUNK  72          // sum over m of (m/2+1)
#define EPSF    1e-6f
#define WPLANE  262144      // 512*512 elements per weight plane

typedef short v8s __attribute__((ext_vector_type(8)));
typedef float v4f __attribute__((ext_vector_type(4)));

static __device__ __forceinline__ v4f mfma16(v8s a, v8s b, v4f c) {
  return __builtin_amdgcn_mfma_f32_16x16x32_bf16(a, b, c, 0, 0, 0);
}
static __device__ __forceinline__ ushort bf16rne(float f) {
  uint32_t u = __float_as_uint(f);
  return (ushort)((u + 0x7fffu + ((u >> 16) & 1u)) >> 16);
}
static __device__ __forceinline__ float bf16f(ushort h) {
  return __uint_as_float(((uint32_t)h) << 16);
}

// ---------------------------------------------------------------------------
// W[k][n] fp32 -> Wt[n][k] bf16 planes; hi+lo for z<2 (Wq,Wk), hi-only z>=2.
__global__ __launch_bounds__(256) void prep_w(const float* __restrict__ W0,
                                              const float* __restrict__ W1,
                                              const float* __restrict__ W2,
                                              const float* __restrict__ W3,
                                              ushort* __restrict__ Wth,
                                              ushort* __restrict__ Wtl) {
  __shared__ float T[64][68];
  const int z = blockIdx.z;
  const float* W = (z == 0) ? W0 : (z == 1) ? W1 : (z == 2) ? W2 : W3;
  const int kb = blockIdx.x * 64;
  const int nb = blockIdx.y * 64;
  const int tid = threadIdx.x;
#pragma unroll
  for (int l = 0; l < 4; ++l) {
    int f = tid + l * 256;           // 64 rows(k) x 16 float4(n)
    int row = f >> 4, c4 = f & 15;
    float4 v = *reinterpret_cast<const float4*>(&W[(size_t)(kb + row) * D_MODEL + nb + c4 * 4]);
    T[c4 * 4 + 0][row] = v.x; T[c4 * 4 + 1][row] = v.y;
    T[c4 * 4 + 2][row] = v.z; T[c4 * 4 + 3][row] = v.w;
  }
  __syncthreads();
  ushort* oh = Wth + (size_t)z * WPLANE;
  ushort* ol = Wtl + (size_t)z * WPLANE;   // valid only z<2
#pragma unroll
  for (int l = 0; l < 4; ++l) {
    int f = tid + l * 256;           // 64 rows(n) x 16 groups of 4(k)
    int n_ = f >> 4, k4 = f & 15;
    ushort4 h4, l4;
    float v0 = T[n_][k4 * 4 + 0], v1 = T[n_][k4 * 4 + 1];
    float v2 = T[n_][k4 * 4 + 2], v3 = T[n_][k4 * 4 + 3];
    h4.x = bf16rne(v0); h4.y = bf16rne(v1); h4.z = bf16rne(v2); h4.w = bf16rne(v3);
    *reinterpret_cast<ushort4*>(&oh[(size_t)(nb + n_) * D_MODEL + kb + k4 * 4]) = h4;
    if (z < 2) {
      l4.x = bf16rne(v0 - bf16f(h4.x)); l4.y = bf16rne(v1 - bf16f(h4.y));
      l4.z = bf16rne(v2 - bf16f(h4.z)); l4.w = bf16rne(v3 - bf16f(h4.w));
      *reinterpret_cast<ushort4*>(&ol[(size_t)(nb + n_) * D_MODEL + kb + k4 * 4]) = l4;
    }
  }
}

// ---------------------------------------------------------------------------
// Q/K: 3-term hi/lo MFMA, outputs hi+lo planes.  V: 1-term bf16 -> Vb plane.
// x (fp32) converted to hi/lo during LDS staging.
__global__ __launch_bounds__(256) void qkv_gemm(
    const float* __restrict__ x, const ushort* __restrict__ Wth,
    const ushort* __restrict__ Wtl,
    const float* __restrict__ bq, const float* __restrict__ bk,
    const float* __restrict__ bv,
    ushort* __restrict__ Qh_, ushort* __restrict__ Ql_,
    ushort* __restrict__ Kh_, ushort* __restrict__ Kl_,
    ushort* __restrict__ Vb_) {
  __shared__ ushort Ah[128][40], Al[128][40], Bh[128][40], Bl[128][40];
  const int z = blockIdx.z;
  const bool hl = (z < 2);
  const ushort* Bth = Wth + (size_t)z * WPLANE;
  const ushort* Btl = Wtl + (size_t)z * WPLANE;
  const float* bias = (z == 0) ? bq : (z == 1) ? bk : bv;
  ushort* outH = (z == 0) ? Qh_ : (z == 1) ? Kh_ : Vb_;
  ushort* outL = (z == 0) ? Ql_ : Kl_;

  const int bx = blockIdx.x, by = blockIdx.y;
  const int tid = threadIdx.x;
  const int wid = tid >> 6, lane = tid & 63;
  const int wr = wid >> 1, wc = wid & 1;
  const int g = lane >> 4, lx = lane & 15;

  v4f acc[4][4];
#pragma unroll
  for (int i = 0; i < 4; ++i)
#pragma unroll
    for (int j = 0; j < 4; ++j) acc[i][j] = v4f{0.f, 0.f, 0.f, 0.f};

  for (int k0 = 0; k0 < 16; ++k0) {
    __syncthreads();
#pragma unroll
    for (int l = 0; l < 4; ++l) {
      int f = tid + l * 256;          // 128 rows x 8 float4 (32 k)
      int row = f >> 3, c4 = f & 7;
      float4 a = *reinterpret_cast<const float4*>(&x[(size_t)(by * 128 + row) * D_MODEL + k0 * 32 + c4 * 4]);
      float av[4] = {a.x, a.y, a.z, a.w};
#pragma unroll
      for (int j = 0; j < 4; ++j) {
        ushort hi = bf16rne(av[j]);
        Ah[row][c4 * 4 + j] = hi;
        if (hl) Al[row][c4 * 4 + j] = bf16rne(av[j] - bf16f(hi));
      }
    }
#pragma unroll
    for (int l = 0; l < 2; ++l) {
      int f = tid + l * 256;          // 128 rows x 4 chunks of 8
      int row = f >> 2, c8 = f & 3;
      *reinterpret_cast<uint4*>(&Bh[row][c8 * 8]) =
          *reinterpret_cast<const uint4*>(&Bth[(size_t)(bx * 128 + row) * D_MODEL + k0 * 32 + c8 * 8]);
      if (hl)
        *reinterpret_cast<uint4*>(&Bl[row][c8 * 8]) =
            *reinterpret_cast<const uint4*>(&Btl[(size_t)(bx * 128 + row) * D_MODEL + k0 * 32 + c8 * 8]);
    }
    __syncthreads();
    v8s ah[4], al[4], bh[4], bl[4];
#pragma unroll
    for (int i = 0; i < 4; ++i) {
      ah[i] = *reinterpret_cast<const v8s*>(&Ah[wr * 64 + i * 16 + lx][g * 8]);
      bh[i] = *reinterpret_cast<const v8s*>(&Bh[wc * 64 + i * 16 + lx][g * 8]);
      if (hl) {
        al[i] = *reinterpret_cast<const v8s*>(&Al[wr * 64 + i * 16 + lx][g * 8]);
        bl[i] = *reinterpret_cast<const v8s*>(&Bl[wc * 64 + i * 16 + lx][g * 8]);
      }
    }
#pragma unroll
    for (int i = 0; i < 4; ++i)
#pragma unroll
      for (int j = 0; j < 4; ++j) {
        acc[i][j] = mfma16(ah[i], bh[j], acc[i][j]);
        if (hl) {
          acc[i][j] = mfma16(ah[i], bl[j], acc[i][j]);
          acc[i][j] = mfma16(al[i], bh[j], acc[i][j]);
        }
      }
  }
#pragma unroll
  for (int j = 0; j < 4; ++j) {
    const int col = bx * 128 + wc * 64 + j * 16 + lx;
    const float bj = bias[col];
#pragma unroll
    for (int i = 0; i < 4; ++i)
#pragma unroll
      for (int r = 0; r < 4; ++r) {
        const int row = by * 128 + wr * 64 + i * 16 + g * 4 + r;
        float v = acc[i][j][r] + bj;
        ushort hi = bf16rne(v);
        outH[(size_t)row * D_MODEL + col] = hi;
        if (hl) outL[(size_t)row * D_MODEL + col] = bf16rne(v - bf16f(hi));
      }
  }
}

// ---------------------------------------------------------------------------
// Vb [n][512] bf16 -> Vtb [h][64][2048] (d-major per head)
__global__ __launch_bounds__(256) void vt_prep(const ushort* __restrict__ Vb,
                                               ushort* __restrict__ Vtb) {
  __shared__ ushort T[64][72];
  const int nb = blockIdx.x * 64;
  const int h  = blockIdx.y;
  const int tid = threadIdx.x;
#pragma unroll
  for (int l = 0; l < 2; ++l) {
    int f = tid + l * 256;            // 64 rows(n) x 8 chunks of 8(d)
    int row = f >> 3, c8 = f & 7;
    uint4 w = *reinterpret_cast<const uint4*>(&Vb[(size_t)(nb + row) * D_MODEL + h * 64 + c8 * 8]);
    const ushort* p = reinterpret_cast<const ushort*>(&w);
#pragma unroll
    for (int j = 0; j < 8; ++j) T[c8 * 8 + j][row] = p[j];
  }
  __syncthreads();
#pragma unroll
  for (int l = 0; l < 2; ++l) {
    int f = tid + l * 256;            // 64 rows(d) x 8 chunks of 8(n)
    int d = f >> 3, n8 = f & 7;
    *reinterpret_cast<uint4*>(&Vtb[(size_t)(h * 64 + d) * NSEQ + nb + n8 * 8]) =
        *reinterpret_cast<const uint4*>(&T[d][n8 * 8]);
  }
}

// ---------------------------------------------------------------------------
// Row norms of Q and K (hi+lo reconstructed): Nout[h][n]
__global__ __launch_bounds__(256) void norms(const ushort* __restrict__ Qh,
                                             const ushort* __restrict__ Ql,
                                             const ushort* __restrict__ Kh,
                                             const ushort* __restrict__ Kl,
                                             float* __restrict__ Qn,
                                             float* __restrict__ Kn) {
  const int z = blockIdx.z;
  const ushort* Hp = z ? Kh : Qh;
  const ushort* Lp = z ? Kl : Ql;
  float* Nout = z ? Kn : Qn;
  const int h = blockIdx.y;
  const int nb = blockIdx.x * 128;
  const int tid = threadIdx.x;
  const int r = tid >> 1, half = tid & 1;
  const size_t base = (size_t)(nb + r) * D_MODEL + h * 64 + half * 32;
  float s = 0.f;
#pragma unroll
  for (int q = 0; q < 4; ++q) {
    uint4 wh = *reinterpret_cast<const uint4*>(&Hp[base + q * 8]);
    uint4 wl = *reinterpret_cast<const uint4*>(&Lp[base + q * 8]);
    const ushort* ph = reinterpret_cast<const ushort*>(&wh);
    const ushort* pl = reinterpret_cast<const ushort*>(&wl);
#pragma unroll
    for (int j = 0; j < 8; ++j) {
      float v = bf16f(ph[j]) + bf16f(pl[j]);
      s = fmaf(v, v, s);
    }
  }
  s += __shfl_xor(s, 1, 64);
  if (half == 0) Nout[h * NSEQ + nb + r] = s;
}

// ---------------------------------------------------------------------------
// Attention. grid (NCHUNK, NHEADS), 512 threads = 8 waves; 2 WG/CU.
// Wave w owns q-rows [16w,16w+16). Q frags in regs; K hi/lo in LDS; V from L2.
__global__ __launch_bounds__(512, 4) void attn(
    const ushort* __restrict__ Qh, const ushort* __restrict__ Ql,
    const ushort* __restrict__ Kh, const ushort* __restrict__ Kl,
    const ushort* __restrict__ Vtb, const float* __restrict__ Qn,
    const float* __restrict__ Kn, const float* __restrict__ cptr,
    float* __restrict__ Opart, float* __restrict__ Npart)
{
  __shared__ ushort Khi[128][68], Klo[128][68];
  __shared__ ushort Es[128][132];
  __shared__ float kns[128];

  const int pid2 = blockIdx.x;
  const int h    = blockIdx.y;
  int m = 0, base = 0;
  while (base + (m / 2 + 1) <= pid2) { base += m / 2 + 1; ++m; }
  const int c  = pid2 - base;
  const int n0 = 2 * c;
  const int n1 = (n0 + 1 < m) ? n0 + 1 : m;

  const int tid  = threadIdx.x;
  const int w    = tid >> 6;
  const int lane = tid & 63;
  const int g = lane >> 4, lx = lane & 15;

  const float cc = fmaxf(fabsf(cptr[0]), 1e-6f);
  const float is = rsqrtf(cc);
  const bool is_one = (cc == 1.0f);
  const float two_cc = 2.f * cc;

  // Q fragments + norms from global
  v8s aQh[2], aQl[2];
  {
    const size_t qoff = (size_t)(m * 128 + 16 * w + lx) * D_MODEL + h * 64 + g * 8;
    aQh[0] = *reinterpret_cast<const v8s*>(&Qh[qoff]);
    aQh[1] = *reinterpret_cast<const v8s*>(&Qh[qoff + 32]);
    aQl[0] = *reinterpret_cast<const v8s*>(&Ql[qoff]);
    aQl[1] = *reinterpret_cast<const v8s*>(&Ql[qoff + 32]);
  }
  float qnr[4], qar[4];
#pragma unroll
  for (int r = 0; r < 4; ++r) {
    qnr[r] = Qn[h * NSEQ + m * 128 + 16 * w + g * 4 + r];
    qar[r] = fmaf(-cc, qnr[r], 1.f);
  }

  v4f o_acc[4];
#pragma unroll
  for (int td = 0; td < 4; ++td) o_acc[td] = v4f{0.f, 0.f, 0.f, 0.f};
  float nrm[4] = {0.f, 0.f, 0.f, 0.f};

  for (int n = n0; n <= n1; ++n) {
    __syncthreads();                  // prev iter's Es/K readers done
    {
      const ushort* Kgh = Kh + (size_t)(n * 128) * D_MODEL + h * 64;
      const ushort* Kgl = Kl + (size_t)(n * 128) * D_MODEL + h * 64;
#pragma unroll
      for (int l = 0; l < 2; ++l) {
        int f = tid + l * 512;        // 128 rows x 8 chunks of 8
        int row = f >> 3, c8 = f & 7;
        *reinterpret_cast<uint4*>(&Khi[row][c8 * 8]) =
            *reinterpret_cast<const uint4*>(&Kgh[(size_t)row * D_MODEL + c8 * 8]);
        *reinterpret_cast<uint4*>(&Klo[row][c8 * 8]) =
            *reinterpret_cast<const uint4*>(&Kgl[(size_t)row * D_MODEL + c8 * 8]);
      }
      if (tid < 128) kns[tid] = Kn[h * NSEQ + n * 128 + tid];
    }
    __syncthreads();

    // ---- S = Q.K^T (3-term hi/lo) ----
    v4f acc[8];
#pragma unroll
    for (int tn = 0; tn < 8; ++tn) acc[tn] = v4f{0.f, 0.f, 0.f, 0.f};
#pragma unroll
    for (int tn = 0; tn < 8; ++tn) {
      v8s bh0 = *reinterpret_cast<const v8s*>(&Khi[tn * 16 + lx][g * 8]);
      v8s bh1 = *reinterpret_cast<const v8s*>(&Khi[tn * 16 + lx][g * 8 + 32]);
      v8s bl0 = *reinterpret_cast<const v8s*>(&Klo[tn * 16 + lx][g * 8]);
      v8s bl1 = *reinterpret_cast<const v8s*>(&Klo[tn * 16 + lx][g * 8 + 32]);
      acc[tn] = mfma16(aQh[0], bh0, acc[tn]);
      acc[tn] = mfma16(aQh[1], bh1, acc[tn]);
      acc[tn] = mfma16(aQh[0], bl0, acc[tn]);
      acc[tn] = mfma16(aQh[1], bl1, acc[tn]);
      acc[tn] = mfma16(aQl[0], bh0, acc[tn]);
      acc[tn] = mfma16(aQl[1], bh1, acc[tn]);
    }

    // ---- u = arg + sqrt(arg^2-1), arg = 1 + t ----
    const bool diag = (n == m);
#pragma unroll
    for (int tn = 0; tn < 8; ++tn) {
      const int col = tn * 16 + lx;
      const float knc = kns[col];
      const float kac = fmaf(-cc, knc, 1.f);
#pragma unroll
      for (int r = 0; r < 4; ++r) {
        const int rowl = 16 * w + g * 4 + r;
        float dsq = fmaxf(fmaf(-2.f, acc[tn][r], qnr[r] + knc), 0.f);
        float den = fmaxf(qar[r] * kac, EPSF);
        float t = fmaxf(two_cc * dsq * __builtin_amdgcn_rcpf(den), EPSF);
        float u = 1.f + t + __builtin_amdgcn_sqrtf(t * (t + 2.f));
        if (diag && col > rowl) u = __builtin_inff();
        acc[tn][r] = u;
      }
    }

    if (is_one) {
      // e = exp(-(acosh_j - acosh_min)) = u_min / u_j  (no log/exp)
      float umin[4] = {__builtin_inff(), __builtin_inff(), __builtin_inff(), __builtin_inff()};
#pragma unroll
      for (int tn = 0; tn < 8; ++tn)
#pragma unroll
        for (int r = 0; r < 4; ++r) umin[r] = fminf(umin[r], acc[tn][r]);
#pragma unroll
      for (int d = 1; d < 16; d <<= 1)
#pragma unroll
        for (int r = 0; r < 4; ++r) umin[r] = fminf(umin[r], __shfl_xor(umin[r], d, 64));
#pragma unroll
      for (int tn = 0; tn < 8; ++tn)
#pragma unroll
        for (int r = 0; r < 4; ++r) {
          float e = umin[r] * __builtin_amdgcn_rcpf(acc[tn][r]);   // inf -> 0
          nrm[r] += e;
          Es[16 * w + g * 4 + r][tn * 16 + lx] = bf16rne(e);
        }
    } else {
      float smax[4] = {-__builtin_inff(), -__builtin_inff(), -__builtin_inff(), -__builtin_inff()};
#pragma unroll
      for (int tn = 0; tn < 8; ++tn)
#pragma unroll
        for (int r = 0; r < 4; ++r) {
          float s = -__logf(acc[tn][r]) * is;      // u=inf -> s=-inf
          acc[tn][r] = s;
          smax[r] = fmaxf(smax[r], s);
        }
#pragma unroll
      for (int d = 1; d < 16; d <<= 1)
#pragma unroll
        for (int r = 0; r < 4; ++r) smax[r] = fmaxf(smax[r], __shfl_xor(smax[r], d, 64));
#pragma unroll
      for (int tn = 0; tn < 8; ++tn)
#pragma unroll
        for (int r = 0; r < 4; ++r) {
          float e = __expf(acc[tn][r] - smax[r]);
          nrm[r] += e;
          Es[16 * w + g * 4 + r][tn * 16 + lx] = bf16rne(e);
        }
    }
    __syncthreads();                  // Es ready

    // ---- o += E @ V (V frags straight from L2) ----
    const ushort* Vg = Vtb + (size_t)(h * 64) * NSEQ + n * 128;
#pragma unroll
    for (int ks = 0; ks < 4; ++ks) {
      v8s ea = *reinterpret_cast<const v8s*>(&Es[16 * w + lx][ks * 32 + g * 8]);
#pragma unroll
      for (int td = 0; td < 4; ++td) {
        v8s vb = *reinterpret_cast<const v8s*>(&Vg[(size_t)(td * 16 + lx) * NSEQ + ks * 32 + g * 8]);
        o_acc[td] = mfma16(ea, vb, o_acc[td]);
      }
    }
  }

  // ---- norm reduce + partial stores ----
#pragma unroll
  for (int d = 1; d < 16; d <<= 1)
#pragma unroll
    for (int r = 0; r < 4; ++r) nrm[r] += __shfl_xor(nrm[r], d, 64);

  float* Op = Opart + ((size_t)h * NCHUNK + pid2) * (128 * 64);
#pragma unroll
  for (int td = 0; td < 4; ++td)
#pragma unroll
    for (int r = 0; r < 4; ++r)
      Op[(size_t)(16 * w + g * 4 + r) * 64 + td * 16 + lx] = o_acc[td][r];
  if (lx == 0) {
#pragma unroll
    for (int r = 0; r < 4; ++r)
      Npart[((size_t)h * NCHUNK + pid2) * 128 + 16 * w + g * 4 + r] = nrm[r];
  }
}

// ---------------------------------------------------------------------------
// Sum partials over chunks, normalize -> Of (f32)
__global__ __launch_bounds__(256) void reduce_o(const float* __restrict__ Opart,
                                                const float* __restrict__ Npart,
                                                float* __restrict__ Of) {
  const int mm = blockIdx.x;
  const int h  = blockIdx.y;
  const int tid = threadIdx.x;
  int base = 0;
  for (int k = 0; k < mm; ++k) base += k / 2 + 1;
  const int nch = mm / 2 + 1;

  __shared__ float innorm[128];
  if (tid < 128) {
    float s = 0.f;
    for (int cI = 0; cI < nch; ++cI)
      s += Npart[((size_t)h * NCHUNK + base + cI) * 128 + tid];
    innorm[tid] = 1.f / fmaxf(s, EPSF);
  }
  __syncthreads();
#pragma unroll
  for (int l = 0; l < 8; ++l) {
    int f = tid + l * 256;            // 128 rows x 16 float4
    int r = f >> 4, c4 = f & 15;
    float4 s = {0.f, 0.f, 0.f, 0.f};
    for (int cI = 0; cI < nch; ++cI) {
      const float4 p = *reinterpret_cast<const float4*>(
          &Opart[((size_t)h * NCHUNK + base + cI) * 8192 + (size_t)r * 64 + c4 * 4]);
      s.x += p.x; s.y += p.y; s.z += p.z; s.w += p.w;
    }
    float inv = innorm[r];
    s.x *= inv; s.y *= inv; s.z *= inv; s.w *= inv;
    *reinterpret_cast<float4*>(
        &Of[(size_t)(mm * 128 + r) * D_MODEL + h * 64 + c4 * 4]) = s;
  }
}

// ---------------------------------------------------------------------------
// out = Of @ Wo + bo, 1-term bf16
__global__ __launch_bounds__(256) void o_gemm(const float* __restrict__ Of,
                                              const ushort* __restrict__ Wth,
                                              const float* __restrict__ bo,
                                              float* __restrict__ out) {
  __shared__ ushort Ah[128][40], Bh[128][40];
  const ushort* Bt = Wth + (size_t)3 * WPLANE;
  const int bx = blockIdx.x, by = blockIdx.y;
  const int tid = threadIdx.x;
  const int wid = tid >> 6, lane = tid & 63;
  const int wr = wid >> 1, wc = wid & 1;
  const int g = lane >> 4, lx = lane & 15;

  v4f acc[4][4];
#pragma unroll
  for (int i = 0; i < 4; ++i)
#pragma unroll
    for (int j = 0; j < 4; ++j) acc[i][j] = v4f{0.f, 0.f, 0.f, 0.f};

  for (int k0 = 0; k0 < 16; ++k0) {
    __syncthreads();
#pragma unroll
    for (int l = 0; l < 4; ++l) {
      int f = tid + l * 256;
      int row = f >> 3, c4 = f & 7;
      float4 a = *reinterpret_cast<const float4*>(&Of[(size_t)(by * 128 + row) * D_MODEL + k0 * 32 + c4 * 4]);
      Ah[row][c4 * 4 + 0] = bf16rne(a.x);
      Ah[row][c4 * 4 + 1] = bf16rne(a.y);
      Ah[row][c4 * 4 + 2] = bf16rne(a.z);
      Ah[row][c4 * 4 + 3] = bf16rne(a.w);
    }
#pragma unroll
    for (int l = 0; l < 2; ++l) {
      int f = tid + l * 256;
      int row = f >> 2, c8 = f & 3;
      *reinterpret_cast<uint4*>(&Bh[row][c8 * 8]) =
          *reinterpret_cast<const uint4*>(&Bt[(size_t)(bx * 128 + row) * D_MODEL + k0 * 32 + c8 * 8]);
    }
    __syncthreads();
    v8s ah[4], bh[4];
#pragma unroll
    for (int i = 0; i < 4; ++i) {
      ah[i] = *reinterpret_cast<const v8s*>(&Ah[wr * 64 + i * 16 + lx][g * 8]);
      bh[i] = *reinterpret_cast<const v8s*>(&Bh[wc * 64 + i * 16 + lx][g * 8]);
    }
#pragma unroll
    for (int i = 0; i < 4; ++i)
#pragma unroll
      for (int j = 0; j < 4; ++j)
        acc[i][j] = mfma16(ah[i], bh[j], acc[i][j]);
  }
#pragma unroll
  for (int j = 0; j < 4; ++j) {
    const int col = bx * 128 + wc * 64 + j * 16 + lx;
    const float bj = bo[col];
#pragma unroll
    for (int i = 0; i < 4; ++i)
#pragma unroll
      for (int r = 0; r < 4; ++r) {
        const int row = by * 128 + wr * 64 + i * 16 + g * 4 + r;
        out[(size_t)row * D_MODEL + col] = acc[i][j][r] + bj;
      }
  }
}

// ---------------------------------------------------------------------------
extern "C" void kernel_launch(void* const* d_in, const int* in_sizes, int n_in,
                              void* d_out, int out_size, void* d_ws, size_t ws_size,
                              hipStream_t stream) {
  (void)in_sizes; (void)n_in; (void)out_size; (void)ws_size;
  const float* x  = (const float*)d_in[0];
  const float* cfg= (const float*)d_in[1];
  const float* Wq = (const float*)d_in[2];
  const float* bq = (const float*)d_in[3];
  const float* Wk = (const float*)d_in[4];
  const float* bk = (const float*)d_in[5];
  const float* Wv = (const float*)d_in[6];
  const float* bv = (const float*)d_in[7];
  const float* Wo = (const float*)d_in[8];
  const float* bo = (const float*)d_in[9];
  float* out = (float*)d_out;

  char* p = (char*)d_ws;
  const size_t PL = (size_t)NSEQ * D_MODEL * sizeof(ushort);   // 2 MiB
  ushort* Wth = (ushort*)p;            p += 4 * (size_t)WPLANE * sizeof(ushort);
  ushort* Wtl = (ushort*)p;            p += 2 * (size_t)WPLANE * sizeof(ushort);
  ushort* Qh  = (ushort*)p;            p += PL;
  ushort* Ql  = (ushort*)p;            p += PL;
  ushort* Kh  = (ushort*)p;            p += PL;
  ushort* Kl  = (ushort*)p;            p += PL;
  ushort* Vb  = (ushort*)p;            p += PL;
  ushort* Vtb = (ushort*)p;            p += PL;
  float*  Qn  = (float*)p;             p += (size_t)NHEADS * NSEQ * sizeof(float);
  float*  Kn  = (float*)p;             p += (size_t)NHEADS * NSEQ * sizeof(float);
  float*  Of  = (float*)p;             p += (size_t)NSEQ * D_MODEL * sizeof(float);
  float*  Opart = (float*)p;           p += (size_t)NHEADS * NCHUNK * 8192 * sizeof(float);
  float*  Npart = (float*)p;

  prep_w<<<dim3(8, 8, 4), 256, 0, stream>>>(Wq, Wk, Wv, Wo, Wth, Wtl);
  qkv_gemm<<<dim3(4, 16, 3), 256, 0, stream>>>(x, Wth, Wtl, bq, bk, bv,
                                               Qh, Ql, Kh, Kl, Vb);
  vt_prep<<<dim3(32, 8), 256, 0, stream>>>(Vb, Vtb);
  norms<<<dim3(16, 8, 2), 256, 0, stream>>>(Qh, Ql, Kh, Kl, Qn, Kn);
  attn<<<dim3(NCHUNK, NHEADS), 512, 0, stream>>>(Qh, Ql, Kh, Kl, Vtb, Qn, Kn, cfg,
                                                 Opart, Npart);
  reduce_o<<<dim3(NBLK, NHEADS), 256, 0, stream>>>(Opart, Npart, Of);
  o_gemm<<<dim3(4, 16), 256, 0, stream>>>(Of, Wth, bo, out);
}